// Round 3
// baseline (854.253 us; speedup 1.0000x reference)
//
#include <hip/hip_runtime.h>
#include <math.h>
#include <stdint.h>
#include <stddef.h>

// ---------------------------------------------------------------------------
// Attention layer for MI355X (gfx950). I/O is fp32 (per reference dtypes).
// Internally: convert x/wq/wk/wv/wo to bf16 once, then bf16-MFMA pipeline:
//   x(2048,4096) @ wq^T -> Q(2048,32,128)   [gemm_bt, bf16]
//   x @ wk^T -> K(2048,8,128), x @ wv^T -> V(2048,8,128)
//   RoPE(Q), RoPE(K)
//   flash attention, causal, GQA rep=4
//   attn(2048,4096) @ wo^T -> out (fp32)    [gemm_bt]
// ---------------------------------------------------------------------------

typedef __attribute__((ext_vector_type(8))) short bf16x8;
typedef __attribute__((ext_vector_type(4))) float f32x4;
typedef unsigned short u16;

#define NEG_BIG (-1.0e9f)   // finite mask sentinel (matches reference's -1e9)

__device__ __forceinline__ float bf2f(u16 b) {
    return __uint_as_float(((unsigned int)b) << 16);
}
__device__ __forceinline__ u16 f2bf(float f) {
    unsigned int u = __float_as_uint(f);
    u += 0x7fff + ((u >> 16) & 1);   // RNE
    return (u16)(u >> 16);
}
__device__ __forceinline__ void gld_lds16(short* lds, const u16* g) {
    __builtin_amdgcn_global_load_lds(
        (const __attribute__((address_space(1))) void*)g,
        (__attribute__((address_space(3))) void*)lds, 16, 0, 0);
}

// ---------------------------------------------------------------------------
// fp32 -> bf16 bulk convert (n multiple of 8)
// ---------------------------------------------------------------------------
__global__ __launch_bounds__(256) void cvt_bf16(const float* __restrict__ src,
                                                u16* __restrict__ dst, int n) {
    int i = (blockIdx.x * blockDim.x + threadIdx.x) * 8;
    if (i >= n) return;
    float4 a, b;
    __builtin_memcpy(&a, src + i, 16);
    __builtin_memcpy(&b, src + i + 4, 16);
    bf16x8 o;
    o[0] = (short)f2bf(a.x); o[1] = (short)f2bf(a.y);
    o[2] = (short)f2bf(a.z); o[3] = (short)f2bf(a.w);
    o[4] = (short)f2bf(b.x); o[5] = (short)f2bf(b.y);
    o[6] = (short)f2bf(b.z); o[7] = (short)f2bf(b.w);
    __builtin_memcpy(dst + i, &o, 16);
}

// ---------------------------------------------------------------------------
// m97-style gemm_bt: C[M,N] = A[M,K] @ B[N,K]^T, bf16 in, fp32 accum.
// 128x128 tile / block (256 thr = 4 waves, each wave 64x64 as 4x4 mfma grid).
// ---------------------------------------------------------------------------
template <bool F32OUT>
__device__ __forceinline__ void gemm_tile_bt(const u16* __restrict__ A,
                                             const u16* __restrict__ B,
                                             void* __restrict__ C,
                                             int mb, int nb, int N, int K,
                                             short* As, short* Bs) {
    const int t = threadIdx.x;
    const int lane = t & 63, wave = t >> 6;
    const int l15 = lane & 15, quad = lane >> 4;
    const int wm = (wave >> 1) * 64, wn = (wave & 1) * 64;
    f32x4 acc[4][4] = {};

    // staging: 512 chunks of 16B per 128x32 tile; 2 chunks/thread/tile
    const int r0 = t >> 2, cc0 = (t & 3) * 8;
    const u16* Ap0 = A + (size_t)(mb * 128 + r0) * K + cc0;
    const u16* Ap1 = Ap0 + (size_t)64 * K;
    const u16* Bp0 = B + (size_t)(nb * 128 + r0) * K + cc0;
    const u16* Bp1 = Bp0 + (size_t)64 * K;
    short* asd0 = As + t * 8; short* asd1 = As + (t + 256) * 8;
    short* bsd0 = Bs + t * 8; short* bsd1 = Bs + (t + 256) * 8;

    int aoff[4], boff[4];
#pragma unroll
    for (int i = 0; i < 4; ++i) {
        aoff[i] = (wm + i * 16 + l15) * 32 + quad * 8;
        boff[i] = (wn + i * 16 + l15) * 32 + quad * 8;
    }

    for (int kb = 0; kb < K; kb += 32) {
        gld_lds16(asd0, Ap0 + kb);
        gld_lds16(asd1, Ap1 + kb);
        gld_lds16(bsd0, Bp0 + kb);
        gld_lds16(bsd1, Bp1 + kb);
        __syncthreads();
        bf16x8 af[4], bfr[4];
#pragma unroll
        for (int i = 0; i < 4; ++i) __builtin_memcpy(&af[i], As + aoff[i], 16);
#pragma unroll
        for (int j = 0; j < 4; ++j) __builtin_memcpy(&bfr[j], Bs + boff[j], 16);
#pragma unroll
        for (int i = 0; i < 4; ++i)
#pragma unroll
            for (int j = 0; j < 4; ++j)
                acc[i][j] = __builtin_amdgcn_mfma_f32_16x16x32_bf16(
                    af[i], bfr[j], acc[i][j], 0, 0, 0);
        __syncthreads();
    }

    // C/D layout: col = lane&15, row = quad*4 + reg  (m89/m91 verified)
#pragma unroll
    for (int i = 0; i < 4; ++i)
#pragma unroll
        for (int j = 0; j < 4; ++j)
#pragma unroll
            for (int r = 0; r < 4; ++r) {
                int row = mb * 128 + wm + i * 16 + quad * 4 + r;
                int col = nb * 128 + wn + j * 16 + l15;
                if (F32OUT)
                    ((float*)C)[(size_t)row * N + col] = acc[i][j][r];
                else
                    ((u16*)C)[(size_t)row * N + col] = f2bf(acc[i][j][r]);
            }
}

__global__ __launch_bounds__(256) void qkv_proj(
    const u16* __restrict__ x,
    const u16* __restrict__ wq, const u16* __restrict__ wk,
    const u16* __restrict__ wv,
    u16* __restrict__ Q, u16* __restrict__ Kc, u16* __restrict__ Vc) {
    __shared__ __align__(16) short As[128 * 32];
    __shared__ __align__(16) short Bs[128 * 32];
    int mb = blockIdx.x, y = blockIdx.y;
    const u16* B; u16* C; int nb, N;
    if (y < 32)      { B = wq; C = Q;  nb = y;      N = 4096; }
    else if (y < 40) { B = wk; C = Kc; nb = y - 32; N = 1024; }
    else             { B = wv; C = Vc; nb = y - 40; N = 1024; }
    gemm_tile_bt<false>(x, B, C, mb, nb, N, 4096, As, Bs);
}

__global__ __launch_bounds__(256) void oproj(
    const u16* __restrict__ A, const u16* __restrict__ wo,
    float* __restrict__ out) {
    __shared__ __align__(16) short As[128 * 32];
    __shared__ __align__(16) short Bs[128 * 32];
    gemm_tile_bt<true>(A, wo, out, blockIdx.x, blockIdx.y, 4096, 4096, As, Bs);
}

// ---------------------------------------------------------------------------
// RoPE in-place: X viewed as (2048, nheads, 64 pairs of 2); cos/sin fp32
// ---------------------------------------------------------------------------
__global__ void rope_kernel(u16* __restrict__ X,
                            const float* __restrict__ cosb,
                            const float* __restrict__ sinb, int nheads) {
    int idx = blockIdx.x * blockDim.x + threadIdx.x;
    int total = 2048 * nheads * 64;
    if (idx >= total) return;
    int i = idx % 64;
    int h = (idx / 64) % nheads;
    int s = idx / (64 * nheads);
    u16* p = X + (size_t)s * nheads * 128 + h * 128 + 2 * i;
    float x0 = bf2f(p[0]), x1 = bf2f(p[1]);
    float c = cosb[s * 64 + i], sn = sinb[s * 64 + i];
    p[0] = f2bf(x0 * c - x1 * sn);
    p[1] = f2bf(x0 * sn + x1 * c);
}

// ---------------------------------------------------------------------------
// Flash attention, causal, GQA (h -> kv h>>2).
// Block = 4 waves; wave w owns q rows [qt*64 + w*16, +16). 32-key blocks.
// S/O in mfma C-layout (row=quad*4+reg, col=lane&15); P round-trips LDS into
// A-layout; V-block transposed into LDS for the B operand.
// ---------------------------------------------------------------------------
__global__ __launch_bounds__(256) void flash_attn(
    const u16* __restrict__ Q, const u16* __restrict__ Kp,
    const u16* __restrict__ Vp, u16* __restrict__ O) {
    __shared__ __align__(16) short Vt[128 * 32];      // [dim][key]
    __shared__ __align__(16) short Pw[4 * 16 * 32];   // per-wave [row][key]
    const int qt = blockIdx.x, h = blockIdx.y;
    const int kvh = h >> 2;
    const int t = threadIdx.x, lane = t & 63, wave = t >> 6;
    const int l15 = lane & 15, quad = lane >> 4;
    const int q0 = qt * 64 + wave * 16;
    const float scale = 0.08838834764831845f;  // 1/sqrt(128)

    // Q fragments (A-layout): lane reads row q0+l15, k-chunk quad*8 (+32*kc)
    bf16x8 qf[4];
    {
        const u16* qp = Q + (size_t)(q0 + l15) * 4096 + h * 128 + quad * 8;
#pragma unroll
        for (int kc = 0; kc < 4; ++kc) __builtin_memcpy(&qf[kc], qp + kc * 32, 16);
    }

    f32x4 o[8] = {};
    float m_i[4], l_i[4];
#pragma unroll
    for (int r = 0; r < 4; ++r) { m_i[r] = NEG_BIG; l_i[r] = 0.f; }

    const int nkb = qt * 2 + 2;  // covers keys 0 .. qt*64+63
    for (int kb = 0; kb < nkb; ++kb) {
        __syncthreads();  // previous iteration's Vt reads done
        // stage V^T: Vt[d][key] = V[kb*32+key][kvh*128+d]
#pragma unroll
        for (int i = 0; i < 2; ++i) {
            int c = t + i * 256;          // 0..511
            int key = c >> 4, d0 = (c & 15) * 8;
            bf16x8 v;
            __builtin_memcpy(&v, Vp + (size_t)(kb * 32 + key) * 1024 +
                                 kvh * 128 + d0, 16);
#pragma unroll
            for (int e = 0; e < 8; ++e) Vt[(d0 + e) * 32 + key] = v[e];
        }
        __syncthreads();

        // S = Q K^T (16q x 32k as two 16x16 n-tiles)
        f32x4 s[2]; s[0] = (f32x4){0,0,0,0}; s[1] = (f32x4){0,0,0,0};
#pragma unroll
        for (int j = 0; j < 2; ++j) {
            const u16* kp = Kp + (size_t)(kb * 32 + j * 16 + l15) * 1024 +
                            kvh * 128 + quad * 8;
#pragma unroll
            for (int kc = 0; kc < 4; ++kc) {
                bf16x8 kf;
                __builtin_memcpy(&kf, kp + kc * 32, 16);
                s[j] = __builtin_amdgcn_mfma_f32_16x16x32_bf16(qf[kc], kf, s[j],
                                                               0, 0, 0);
            }
        }

        // scale + causal mask (finite sentinel)
        float sv[2][4];
#pragma unroll
        for (int j = 0; j < 2; ++j) {
            int key = kb * 32 + j * 16 + l15;
#pragma unroll
            for (int r = 0; r < 4; ++r) {
                int row = q0 + quad * 4 + r;
                sv[j][r] = (key <= row) ? s[j][r] * scale : NEG_BIG;
            }
        }

        // online softmax (reduce across the 16 lanes of each quad)
        float mnew[4], alpha[4];
#pragma unroll
        for (int r = 0; r < 4; ++r) {
            float mx = fmaxf(sv[0][r], sv[1][r]);
#pragma unroll
            for (int off = 1; off <= 8; off <<= 1)
                mx = fmaxf(mx, __shfl_xor(mx, off));
            mnew[r] = fmaxf(m_i[r], mx);
            alpha[r] = __expf(m_i[r] - mnew[r]);  // exp(-1e9-m) underflows to 0
        }
        float p[2][4];
#pragma unroll
        for (int r = 0; r < 4; ++r) {
#pragma unroll
            for (int j = 0; j < 2; ++j) p[j][r] = __expf(sv[j][r] - mnew[r]);
            float sm = p[0][r] + p[1][r];
#pragma unroll
            for (int off = 1; off <= 8; off <<= 1) sm += __shfl_xor(sm, off);
            l_i[r] = l_i[r] * alpha[r] + sm;
            m_i[r] = mnew[r];
        }
#pragma unroll
        for (int n = 0; n < 8; ++n)
#pragma unroll
            for (int r = 0; r < 4; ++r) o[n][r] *= alpha[r];

        // P: C-layout regs -> LDS -> A-layout frag (per-wave region)
        short* pw = Pw + wave * 512;
#pragma unroll
        for (int j = 0; j < 2; ++j)
#pragma unroll
            for (int r = 0; r < 4; ++r)
                pw[(quad * 4 + r) * 32 + j * 16 + l15] = (short)f2bf(p[j][r]);
        asm volatile("" ::: "memory");  // forbid compiler write/read reorder
        bf16x8 pf;
        __builtin_memcpy(&pf, pw + l15 * 32 + quad * 8, 16);

        // O += P V  (8 n-tiles over the 128 dims)
#pragma unroll
        for (int n = 0; n < 8; ++n) {
            bf16x8 vf;
            __builtin_memcpy(&vf, Vt + (n * 16 + l15) * 32 + quad * 8, 16);
            o[n] = __builtin_amdgcn_mfma_f32_16x16x32_bf16(pf, vf, o[n], 0, 0, 0);
        }
    }

    // epilogue: O / l
#pragma unroll
    for (int n = 0; n < 8; ++n)
#pragma unroll
        for (int r = 0; r < 4; ++r) {
            int row = q0 + quad * 4 + r;
            O[(size_t)row * 4096 + h * 128 + n * 16 + l15] =
                f2bf(o[n][r] / l_i[r]);
        }
}

// ---------------------------------------------------------------------------
extern "C" void kernel_launch(void* const* d_in, const int* in_sizes, int n_in,
                              void* d_out, int out_size, void* d_ws,
                              size_t ws_size, hipStream_t stream) {
    const float* x  = (const float*)d_in[0];
    const float* wq = (const float*)d_in[1];
    const float* wk = (const float*)d_in[2];
    const float* wv = (const float*)d_in[3];
    const float* wo = (const float*)d_in[4];
    const float* fc = (const float*)d_in[5];
    const float* fs = (const float*)d_in[6];
    // d_in[7] = mask: causal, applied analytically in flash_attn
    float* out = (float*)d_out;

    const int NX = 2048 * 4096;   // x / Q / Ao elements
    const int NQW = 4096 * 4096;  // wq / wo
    const int NKW = 1024 * 4096;  // wk / wv
    const int NKV = 2048 * 1024;  // K / V

    u16* Q   = (u16*)d_ws;           // 2048*4096
    u16* Kc  = Q   + NX;             // 2048*1024
    u16* Vc  = Kc  + NKV;            // 2048*1024
    u16* Ao  = Vc  + NKV;            // 2048*4096
    u16* xb  = Ao  + NX;             // 2048*4096
    u16* wqb = xb  + NX;             // 4096*4096
    u16* wkb = wqb + NQW;            // 1024*4096
    u16* wvb = wkb + NKW;            // 1024*4096
    u16* wob = wvb + NKW;            // 4096*4096
    // total 71,303,168 u16 = 136 MiB of ws

    cvt_bf16<<<NX / (256 * 8), 256, 0, stream>>>(x, xb, NX);
    cvt_bf16<<<NQW / (256 * 8), 256, 0, stream>>>(wq, wqb, NQW);
    cvt_bf16<<<NKW / (256 * 8), 256, 0, stream>>>(wk, wkb, NKW);
    cvt_bf16<<<NKW / (256 * 8), 256, 0, stream>>>(wv, wvb, NKW);
    cvt_bf16<<<NQW / (256 * 8), 256, 0, stream>>>(wo, wob, NQW);

    qkv_proj<<<dim3(16, 48), 256, 0, stream>>>(xb, wqb, wkb, wvb, Q, Kc, Vc);
    rope_kernel<<<(2048 * 32 * 64 + 255) / 256, 256, 0, stream>>>(Q, fc, fs, 32);
    rope_kernel<<<(2048 * 8 * 64 + 255) / 256, 256, 0, stream>>>(Kc, fc, fs, 8);
    flash_attn<<<dim3(32, 32), 256, 0, stream>>>(Q, Kc, Vc, Ao);
    oproj<<<dim3(16, 32), 256, 0, stream>>>(Ao, wob, out);
}

// Round 5
// 674.370 us; speedup vs baseline: 1.2667x; 1.2667x over previous
//
#include <hip/hip_runtime.h>
#include <math.h>
#include <stdint.h>
#include <stddef.h>

// ---------------------------------------------------------------------------
// Attention layer for MI355X (gfx950). I/O fp32; internal bf16 MFMA pipeline.
//   cvt: x/wq/wk/wv/wo -> bf16
//   qkv_proj (gemm_bt): Q(2048,4096), K(2048,1024), V -> V^T(1024,2048)
//   RoPE(Q), RoPE(K)
//   flash_attn: LDS-free, key-permuted S^T trick, causal, GQA rep=4
//   oproj (gemm_bt): out fp32
// Only mfma_f32_16x16x32_bf16 is used (HW-verified layouts m89/m97).
// ---------------------------------------------------------------------------

typedef __attribute__((ext_vector_type(8))) short bf16x8;
typedef __attribute__((ext_vector_type(4))) short bf16x4;
typedef __attribute__((ext_vector_type(4))) float f32x4;
typedef unsigned short u16;

#define NEG_BIG (-1.0e9f)
#define MFMA32(a, b, c) __builtin_amdgcn_mfma_f32_16x16x32_bf16(a, b, c, 0, 0, 0)

__device__ __forceinline__ float bf2f(u16 b) {
    return __uint_as_float(((unsigned int)b) << 16);
}
__device__ __forceinline__ u16 f2bf(float f) {
    unsigned int u = __float_as_uint(f);
    u += 0x7fff + ((u >> 16) & 1);   // RNE
    return (u16)(u >> 16);
}
__device__ __forceinline__ void gld_lds16(short* lds, const u16* g) {
    __builtin_amdgcn_global_load_lds(
        (const __attribute__((address_space(1))) void*)g,
        (__attribute__((address_space(3))) void*)lds, 16, 0, 0);
}

// ---------------------------------------------------------------------------
// fp32 -> bf16 bulk convert (n multiple of 8)
// ---------------------------------------------------------------------------
__global__ __launch_bounds__(256) void cvt_bf16(const float* __restrict__ src,
                                                u16* __restrict__ dst, int n) {
    int i = (blockIdx.x * blockDim.x + threadIdx.x) * 8;
    if (i >= n) return;
    float4 a, b;
    __builtin_memcpy(&a, src + i, 16);
    __builtin_memcpy(&b, src + i + 4, 16);
    bf16x8 o;
    o[0] = (short)f2bf(a.x); o[1] = (short)f2bf(a.y);
    o[2] = (short)f2bf(a.z); o[3] = (short)f2bf(a.w);
    o[4] = (short)f2bf(b.x); o[5] = (short)f2bf(b.y);
    o[6] = (short)f2bf(b.z); o[7] = (short)f2bf(b.w);
    __builtin_memcpy(dst + i, &o, 16);
}

// ---------------------------------------------------------------------------
// m97-style gemm_bt: C = A[M,K] @ B[N,K]^T, bf16 in, fp32 accum.
// OUT: 0 = bf16 row-major, 1 = fp32 row-major, 2 = bf16 transposed [N][2048]
// ---------------------------------------------------------------------------
template <int OUT>
__device__ __forceinline__ void gemm_tile_bt(const u16* __restrict__ A,
                                             const u16* __restrict__ B,
                                             void* __restrict__ C,
                                             int mb, int nb, int N, int K,
                                             short* As, short* Bs) {
    const int t = threadIdx.x;
    const int lane = t & 63, wave = t >> 6;
    const int l15 = lane & 15, quad = lane >> 4;
    const int wm = (wave >> 1) * 64, wn = (wave & 1) * 64;
    f32x4 acc[4][4] = {};

    const int r0 = t >> 2, cc0 = (t & 3) * 8;
    const u16* Ap0 = A + (size_t)(mb * 128 + r0) * K + cc0;
    const u16* Ap1 = Ap0 + (size_t)64 * K;
    const u16* Bp0 = B + (size_t)(nb * 128 + r0) * K + cc0;
    const u16* Bp1 = Bp0 + (size_t)64 * K;
    short* asd0 = As + t * 8; short* asd1 = As + (t + 256) * 8;
    short* bsd0 = Bs + t * 8; short* bsd1 = Bs + (t + 256) * 8;

    int aoff[4], boff[4];
#pragma unroll
    for (int i = 0; i < 4; ++i) {
        aoff[i] = (wm + i * 16 + l15) * 32 + quad * 8;
        boff[i] = (wn + i * 16 + l15) * 32 + quad * 8;
    }

    for (int kb = 0; kb < K; kb += 32) {
        gld_lds16(asd0, Ap0 + kb);
        gld_lds16(asd1, Ap1 + kb);
        gld_lds16(bsd0, Bp0 + kb);
        gld_lds16(bsd1, Bp1 + kb);
        __syncthreads();
        bf16x8 af[4], bfr[4];
#pragma unroll
        for (int i = 0; i < 4; ++i) __builtin_memcpy(&af[i], As + aoff[i], 16);
#pragma unroll
        for (int j = 0; j < 4; ++j) __builtin_memcpy(&bfr[j], Bs + boff[j], 16);
#pragma unroll
        for (int i = 0; i < 4; ++i)
#pragma unroll
            for (int j = 0; j < 4; ++j)
                acc[i][j] = MFMA32(af[i], bfr[j], acc[i][j]);
        __syncthreads();
    }

    // C/D layout: col = lane&15, row = quad*4 + reg
#pragma unroll
    for (int i = 0; i < 4; ++i)
#pragma unroll
        for (int j = 0; j < 4; ++j) {
            if (OUT == 2) {
                // transposed write: [col][seq], 4 consecutive rows -> 8B store
                int col = nb * 128 + wn + j * 16 + l15;
                int row0 = mb * 128 + wm + i * 16 + quad * 4;
                bf16x4 v;
#pragma unroll
                for (int r = 0; r < 4; ++r) v[r] = (short)f2bf(acc[i][j][r]);
                __builtin_memcpy((u16*)C + (size_t)col * 2048 + row0, &v, 8);
            } else {
#pragma unroll
                for (int r = 0; r < 4; ++r) {
                    int row = mb * 128 + wm + i * 16 + quad * 4 + r;
                    int col = nb * 128 + wn + j * 16 + l15;
                    if (OUT == 1)
                        ((float*)C)[(size_t)row * N + col] = acc[i][j][r];
                    else
                        ((u16*)C)[(size_t)row * N + col] = f2bf(acc[i][j][r]);
                }
            }
        }
}

__global__ __launch_bounds__(256) void qkv_proj(
    const u16* __restrict__ x,
    const u16* __restrict__ wq, const u16* __restrict__ wk,
    const u16* __restrict__ wv,
    u16* __restrict__ Q, u16* __restrict__ Kc, u16* __restrict__ Vt) {
    __shared__ __align__(16) short As[128 * 32];
    __shared__ __align__(16) short Bs[128 * 32];
    int mb = blockIdx.x, y = blockIdx.y;
    if (y < 32)
        gemm_tile_bt<0>(x, wq, Q, mb, y, 4096, 4096, As, Bs);
    else if (y < 40)
        gemm_tile_bt<0>(x, wk, Kc, mb, y - 32, 1024, 4096, As, Bs);
    else
        gemm_tile_bt<2>(x, wv, Vt, mb, y - 40, 1024, 4096, As, Bs);
}

__global__ __launch_bounds__(256) void oproj(
    const u16* __restrict__ A, const u16* __restrict__ wo,
    float* __restrict__ out) {
    __shared__ __align__(16) short As[128 * 32];
    __shared__ __align__(16) short Bs[128 * 32];
    gemm_tile_bt<1>(A, wo, out, blockIdx.x, blockIdx.y, 4096, 4096, As, Bs);
}

// ---------------------------------------------------------------------------
// RoPE in-place: X viewed as (2048, nheads, 64 pairs of 2); cos/sin fp32
// ---------------------------------------------------------------------------
__global__ void rope_kernel(u16* __restrict__ X,
                            const float* __restrict__ cosb,
                            const float* __restrict__ sinb, int nheads) {
    int idx = blockIdx.x * blockDim.x + threadIdx.x;
    int total = 2048 * nheads * 64;
    if (idx >= total) return;
    int i = idx % 64;
    int h = (idx / 64) % nheads;
    int s = idx / (64 * nheads);
    u16* p = X + (size_t)s * nheads * 128 + h * 128 + 2 * i;
    float x0 = bf2f(p[0]), x1 = bf2f(p[1]);
    float c = cosb[s * 64 + i], sn = sinb[s * 64 + i];
    p[0] = f2bf(x0 * c - x1 * sn);
    p[1] = f2bf(x0 * sn + x1 * c);
}

// ---------------------------------------------------------------------------
// LDS-free flash attention with key-permuted S^T.
// S^T = K.Q^T via mfma_16x16x32, with K rows permuted so the C-layout lane
// (quad,c) holds keys kb+8*quad+{0..3} (s0) and +4..7 (s1). That IS the
// 16x16x32 A-operand layout (k=quad*8+j) -> P feeds PV with zero movement.
// V pre-transposed globally: Vt[feature][seq]; PV B-frag = 16B contiguous.
// ---------------------------------------------------------------------------
__device__ __forceinline__ void fa_iter(
    int kb, bool masked, int q0, int l15, int quad,
    const u16* __restrict__ kb0, const u16* __restrict__ vb0,
    const bf16x8 (&qf)[4], f32x4 (&o)[8], float& m, float& l) {
    const float scale = 0.08838834764831845f;  // 1/sqrt(128)

    // S^T = K.Q^T : two 16-key subtiles, key-permuted (see kb0 in fa_task)
    f32x4 s0 = {0, 0, 0, 0}, s1 = {0, 0, 0, 0};
    const u16* ka = kb0 + (size_t)kb * 1024;
    bf16x8 kf0[4], kf1[4];
#pragma unroll
    for (int c = 0; c < 4; ++c) {
        __builtin_memcpy(&kf0[c], ka + c * 32, 16);
        __builtin_memcpy(&kf1[c], ka + 4 * 1024 + c * 32, 16);
    }
#pragma unroll
    for (int c = 0; c < 4; ++c) {
        s0 = MFMA32(kf0[c], qf[c], s0);
        s1 = MFMA32(kf1[c], qf[c], s1);
    }

    // scale + causal mask. Lane (quad,l15): s0[r] = key kb+8*quad+r,
    // s1[r] = key kb+8*quad+4+r, q column = l15.
    float sv0[4], sv1[4];
    const int q = q0 + l15;
#pragma unroll
    for (int r = 0; r < 4; ++r) {
        sv0[r] = s0[r] * scale;
        sv1[r] = s1[r] * scale;
        if (masked) {
            if (kb + 8 * quad + r > q) sv0[r] = NEG_BIG;
            if (kb + 8 * quad + 4 + r > q) sv1[r] = NEG_BIG;
        }
    }

    // online softmax: all 32 keys of q-col l15 spread across quads
    float mx = fmaxf(fmaxf(fmaxf(sv0[0], sv0[1]), fmaxf(sv0[2], sv0[3])),
                     fmaxf(fmaxf(sv1[0], sv1[1]), fmaxf(sv1[2], sv1[3])));
    mx = fmaxf(mx, __shfl_xor(mx, 16));
    mx = fmaxf(mx, __shfl_xor(mx, 32));
    float mnew = fmaxf(m, mx);
    float alpha = __expf(m - mnew);
    float p0[4], p1[4], sum = 0.f;
#pragma unroll
    for (int r = 0; r < 4; ++r) {
        p0[r] = __expf(sv0[r] - mnew);
        p1[r] = __expf(sv1[r] - mnew);
        sum += p0[r] + p1[r];
    }
    sum += __shfl_xor(sum, 16);
    sum += __shfl_xor(sum, 32);
    l = l * alpha + sum;
    m = mnew;

    // broadcast alpha from q=l15 lanes to O's q=quad*4+r rows
    float aO[4];
#pragma unroll
    for (int r = 0; r < 4; ++r) aO[r] = __shfl(alpha, quad * 20 + r);
#pragma unroll
    for (int n = 0; n < 8; ++n)
#pragma unroll
        for (int r = 0; r < 4; ++r) o[n][r] *= aO[r];

    // pack P into the 16x16x32 A-frag: element j = key 8*quad+j  (zero move)
    bf16x8 pa;
#pragma unroll
    for (int r = 0; r < 4; ++r) {
        pa[r] = (short)f2bf(p0[r]);
        pa[4 + r] = (short)f2bf(p1[r]);
    }

    // O += P.V : B-frag = Vt[feature n0+l15][keys kb+quad*8 .. +7], 16B load
    const u16* va = vb0 + kb;
#pragma unroll
    for (int n = 0; n < 8; ++n) {
        bf16x8 v;
        __builtin_memcpy(&v, va + (size_t)n * 16 * 2048, 16);
        o[n] = MFMA32(pa, v, o[n]);
    }
}

__device__ __forceinline__ void fa_task(
    const u16* __restrict__ Q, const u16* __restrict__ Kp,
    const u16* __restrict__ Vt, u16* __restrict__ O,
    int q0, int h, int kvh, int l15, int quad) {
    // Q B-frags (n=q=l15, k=d chunks)
    bf16x8 qf[4];
    const u16* qp = Q + (size_t)(q0 + l15) * 4096 + h * 128 + quad * 8;
#pragma unroll
    for (int c = 0; c < 4; ++c) __builtin_memcpy(&qf[c], qp + c * 32, 16);

    f32x4 o[8] = {};
    float m = NEG_BIG, l = 0.f;

    // key-permuted K base: A-row l15 of s0 loads key row 8*(l15>>2)+(l15&3)
    const int krow = 8 * (l15 >> 2) + (l15 & 3);
    const u16* kb0 = Kp + (size_t)krow * 1024 + kvh * 128 + quad * 8;
    const u16* vb0 = Vt + (size_t)(kvh * 128 + l15) * 2048 + quad * 8;

    const int n32 = (q0 + 47) / 32;  // 32-key blocks; only the last is masked
    for (int kb = 0; kb < (n32 - 1) * 32; kb += 32)
        fa_iter(kb, false, q0, l15, quad, kb0, vb0, qf, o, m, l);
    fa_iter((n32 - 1) * 32, true, q0, l15, quad, kb0, vb0, qf, o, m, l);

    // epilogue: O rows are q=quad*4+r; fetch l from q=l15 lanes
    float inv[4];
#pragma unroll
    for (int r = 0; r < 4; ++r) inv[r] = 1.f / __shfl(l, quad * 20 + r);
#pragma unroll
    for (int n = 0; n < 8; ++n)
#pragma unroll
        for (int r = 0; r < 4; ++r) {
            int row = q0 + quad * 4 + r;
            O[(size_t)row * 4096 + h * 128 + n * 16 + l15] =
                f2bf(o[n][r] * inv[r]);
        }
}

__global__ __launch_bounds__(256) void flash_attn(
    const u16* __restrict__ Q, const u16* __restrict__ Kp,
    const u16* __restrict__ Vt, u16* __restrict__ O) {
    const int pp = blockIdx.x;   // 0..15  (q-tile pair: pp and 31-pp)
    const int h = blockIdx.y;    // 0..31
    const int kvh = h >> 2;
    const int lane = threadIdx.x & 63, wave = threadIdx.x >> 6;
    const int l15 = lane & 15, quad = lane >> 4;
    // wave w of tile pp pairs with wave 3-w of tile 31-pp: 65 iters/wave, flat
    fa_task(Q, Kp, Vt, O, pp * 64 + wave * 16, h, kvh, l15, quad);
    fa_task(Q, Kp, Vt, O, (31 - pp) * 64 + (3 - wave) * 16, h, kvh, l15, quad);
}

// ---------------------------------------------------------------------------
extern "C" void kernel_launch(void* const* d_in, const int* in_sizes, int n_in,
                              void* d_out, int out_size, void* d_ws,
                              size_t ws_size, hipStream_t stream) {
    const float* x  = (const float*)d_in[0];
    const float* wq = (const float*)d_in[1];
    const float* wk = (const float*)d_in[2];
    const float* wv = (const float*)d_in[3];
    const float* wo = (const float*)d_in[4];
    const float* fc = (const float*)d_in[5];
    const float* fs = (const float*)d_in[6];
    float* out = (float*)d_out;

    const int NX = 2048 * 4096;
    const int NQW = 4096 * 4096;
    const int NKW = 1024 * 4096;
    const int NKV = 2048 * 1024;

    u16* Q   = (u16*)d_ws;
    u16* Kc  = Q   + NX;
    u16* Vt  = Kc  + NKV;   // [1024 features][2048 seq]
    u16* Ao  = Vt  + NKV;
    u16* xb  = Ao  + NX;
    u16* wqb = xb  + NX;
    u16* wkb = wqb + NQW;
    u16* wvb = wkb + NKW;
    u16* wob = wvb + NKW;

    cvt_bf16<<<NX / (256 * 8), 256, 0, stream>>>(x, xb, NX);
    cvt_bf16<<<NQW / (256 * 8), 256, 0, stream>>>(wq, wqb, NQW);
    cvt_bf16<<<NKW / (256 * 8), 256, 0, stream>>>(wk, wkb, NKW);
    cvt_bf16<<<NKW / (256 * 8), 256, 0, stream>>>(wv, wvb, NKW);
    cvt_bf16<<<NQW / (256 * 8), 256, 0, stream>>>(wo, wob, NQW);

    qkv_proj<<<dim3(16, 48), 256, 0, stream>>>(xb, wqb, wkb, wvb, Q, Kc, Vt);
    rope_kernel<<<(2048 * 32 * 64 + 255) / 256, 256, 0, stream>>>(Q, fc, fs, 32);
    rope_kernel<<<(2048 * 8 * 64 + 255) / 256, 256, 0, stream>>>(Kc, fc, fs, 8);
    flash_attn<<<dim3(16, 32), 256, 0, stream>>>(Q, Kc, Vt, Ao);
    oproj<<<dim3(16, 32), 256, 0, stream>>>(Ao, wob, out);
}